// Round 6
// baseline (188.025 us; speedup 1.0000x reference)
//
#include <hip/hip_runtime.h>
#include <math.h>

#define NNODES 1024
#define EDGES 16384
#define EB 4   // edges per block in edge_main (one edge per wave)

typedef __attribute__((ext_vector_type(8))) short short8;
typedef __attribute__((ext_vector_type(4))) float f32x4;

__device__ __forceinline__ unsigned short f2bf(float f) {
  union { float f; unsigned int u; } v; v.f = f;
  unsigned int r = v.u + 0x7fffu + ((v.u >> 16) & 1u);
  return (unsigned short)(r >> 16);
}

// ---------------- path tables ----------------
__device__ __constant__ int PL1[13] = {0,1,2, 0,1,1,2,3, 0,1,2,2,3};
__device__ __constant__ int PL2[13] = {0,1,2, 1,0,2,1,2, 2,1,0,2,1};
__device__ __constant__ int PL3[13] = {0,0,0, 1,1,1,1,1, 2,2,2,2,2};
__device__ __constant__ int PCG[13] = {0,1,10, 35,44,53,98,143, 248,273,318,343,468};

// ---------------- SH polynomial tables (2 terms max per lm; coeff 0 = absent) ----
// lm order: l0:0, l1:1..3, l2:4..8, l3:9..15 (matches reference _SHP flattening)
__device__ __constant__ double SHC[16][2] = {
  {1.0, 0.0},
  {1.7320508075688772, 0.0},
  {1.7320508075688772, 0.0},
  {1.7320508075688772, 0.0},
  {3.8729833462074170, 0.0},
  {3.8729833462074170, 0.0},
  {3.3541019662496844, -1.1180339887498949},   // 1.5*S5, -0.5*S5
  {3.8729833462074170, 0.0},
  {1.9364916731037085, -1.9364916731037085},   // 0.5*S15, -0.5*S15
  {6.2749501990055667, -2.0916500663351889},   // 3*C33, -C33
  {10.246950765959598, 0.0},                   // CXYZ
  {8.1009258730098255, -1.6201851746019651},   // 5*C31, -C31
  {6.6143782776614768, -3.9686269665968861},   // 5*C30, -3*C30
  {8.1009258730098255, -1.6201851746019651},
  {5.1234753829797990, -5.1234753829797990},   // C32, -C32
  {2.0916500663351889, -6.2749501990055667},   // C33, -3*C33
};
// exponents packed ex | ey<<4 | ez<<8
__device__ __constant__ int SHE[16][2] = {
  {0,0},{1,0},{16,0},{256,0},
  {17,0},{272,0},{512,0},{257,0},{2,32},
  {18,48},{273,0},{528,16},{768,256},{513,1},{258,288},{3,33}};

// ---------------- k0: zero per-node counters (also first-in-graph absorber) ----
__global__ void k0(int* __restrict__ counts) {
  counts[blockIdx.x*256 + threadIdx.x] = 0;
}

// ---------------- prep: CG (b0-12) + ACT partials (b13-20) + weight pack (b21-52) ----
__global__ __launch_bounds__(256) void prep(
    const float* __restrict__ Wv1, const float* __restrict__ Wv2,
    const float* __restrict__ W1, const float* __restrict__ W2, const float* __restrict__ W3,
    unsigned short* __restrict__ wv1f, unsigned short* __restrict__ wv2f,
    unsigned short* __restrict__ w1f, unsigned short* __restrict__ w2f,
    unsigned short* __restrict__ w3f,
    float* __restrict__ cg, float* __restrict__ actp)
{
  const int bid = blockIdx.x;
  const int t = threadIdx.x;

  if (bid < 13) {
    // ---- CG tensor for path bid: scratch-free, fully unrolled ----
    __shared__ double sh[256];
    const int p = bid;
    const int LOFF[4] = {0,1,4,9};
    int l1 = PL1[p], l2 = PL2[p], l3 = PL3[p];
    int n1 = 2*l1+1, n2 = 2*l2+1, n3 = 2*l3+1;
    int nent = n1*n2*n3;
    // df(n-1) for n=0..8, 7 bits each: {1,1,1,2,3,8,15,48,105}
    const unsigned long long DP =
        1ULL | (1ULL<<7) | (1ULL<<14) | (2ULL<<21) | (3ULL<<28)
      | (8ULL<<35) | (15ULL<<42) | (48ULL<<49) | (105ULL<<56);
    double v = 0.0;
    if (t < nent) {
      int i = t / (n2*n3);
      int rem = t - i*(n2*n3);
      int j = rem / n3;
      int k = rem - j*n3;
      int lm1 = LOFF[l1]+i, lm2 = LOFF[l2]+j, lm3 = LOFF[l3]+k;
      double c1a = SHC[lm1][0], c1b = SHC[lm1][1];
      double c2a = SHC[lm2][0], c2b = SHC[lm2][1];
      double c3a = SHC[lm3][0], c3b = SHC[lm3][1];
      int e1a = SHE[lm1][0], e1b = SHE[lm1][1];
      int e2a = SHE[lm2][0], e2b = SHE[lm2][1];
      int e3a = SHE[lm3][0], e3b = SHE[lm3][1];
      double cs1[2] = {c1a, c1b}; int es1[2] = {e1a, e1b};
      double cs2[2] = {c2a, c2b}; int es2[2] = {e2a, e2b};
      double cs3[2] = {c3a, c3b}; int es3[2] = {e3a, e3b};
      #pragma unroll
      for (int t1 = 0; t1 < 2; t1++)
      #pragma unroll
      for (int t2 = 0; t2 < 2; t2++)
      #pragma unroll
      for (int t3 = 0; t3 < 2; t3++) {
        double cc = cs1[t1]*cs2[t2]*cs3[t3];
        int s = es1[t1] + es2[t2] + es3[t3];   // nibble sums, no carries (each <= 9)
        int a = s & 15, b = (s >> 4) & 15, c = (s >> 8) & 15;
        if (!((a|b|c) & 1)) {
          double num = (double)(int)((DP >> (7*a)) & 127)
                     * (double)(int)((DP >> (7*b)) & 127)
                     * (double)(int)((DP >> (7*c)) & 127);
          double den = (double)(int)((DP >> (7*(a+b+c+2))) & 127);
          v += cc * (num / den);
        }
      }
    }
    sh[t] = (t < nent) ? v*v : 0.0;
    __syncthreads();
    for (int d = 128; d > 0; d >>= 1) {
      if (t < d) sh[t] += sh[t+d];
      __syncthreads();
    }
    double scale = sqrt((double)(2*l3+1)) / sqrt(sh[0]);
    if (t < nent) cg[PCG[p] + t] = (float)(v * scale);

  } else if (bid < 21) {
    // ---- ACT_C partial sums (float; 8 blocks x 256 threads over 200001 pts) ----
    __shared__ float shf[256];
    const int b = bid - 13;
    const float dz = 24.0f / 200000.0f;
    float s = 0.f;
    for (int i = b*256 + t; i <= 200000; i += 8*256) {
      float z = -12.0f + dz * (float)i;
      float ph = __expf(-0.5f * z * z) * 0.3989422804014327f;
      float sl = z / (1.f + __expf(-z));
      s = fmaf(sl*sl, ph, s);
    }
    shf[t] = s;
    __syncthreads();
    for (int d = 128; d > 0; d >>= 1) {
      if (t < d) shf[t] += shf[t + d];
      __syncthreads();
    }
    if (t == 0) actp[b] = shf[0];

  } else {
    // ---- weight fragment pack: 4 fragments per block ----
    const int wid = t >> 6, lane = t & 63;
    const int g = (bid - 21)*4 + wid;
    const float* src; unsigned short* dst; int nk, f;
    if (g < 40)       { src = Wv1; dst = wv1f; nk = 10; f = g; }
    else if (g < 80)  { src = Wv2; dst = wv2f; nk = 10; f = g - 40; }
    else if (g < 112) { src = W1;  dst = w1f;  nk = 8;  f = g - 80; }
    else if (g < 120) { src = W2;  dst = w2f;  nk = 2;  f = g - 112; }
    else              { src = W3;  dst = w3f;  nk = 2;  f = g - 120; }
    int nt = f / nk;
    int ks = f - nt*nk;
    unsigned short us[8];
    #pragma unroll
    for (int j = 0; j < 8; j++) {
      float v = src[(ks*32 + (lane>>4)*8 + j)*64 + nt*16 + (lane & 15)];
      us[j] = f2bf(v);
    }
    uint4 pk;
    pk.x = (unsigned)us[0] | ((unsigned)us[1] << 16);
    pk.y = (unsigned)us[2] | ((unsigned)us[3] << 16);
    pk.z = (unsigned)us[4] | ((unsigned)us[5] << 16);
    pk.w = (unsigned)us[6] | ((unsigned)us[7] << 16);
    *(uint4*)(dst + ((size_t)f*64 + lane)*8) = pk;
  }
}

// ---------------- edgepass: w = x @ W_w / 8, plus bucket scatter ----------------
__global__ __launch_bounds__(256) void edgepass(
    const float* __restrict__ x, const float* __restrict__ Ww,
    const int* __restrict__ senders,
    float* __restrict__ w_ws, int* __restrict__ counts, int* __restrict__ elist, int E)
{
  const int wid = threadIdx.x >> 6, lane = threadIdx.x & 63;
  const int e = blockIdx.x * 4 + wid;
  if (e >= E) return;
  float xv = x[e*64 + lane];
  float w = 0.f;
  #pragma unroll
  for (int f = 0; f < 64; f++)
    w = fmaf(__shfl(xv, f), Ww[f*64 + lane], w);
  w_ws[e*64 + lane] = w * 0.125f;
  if (lane == 0) {
    int s = senders[e];
    int pos = atomicAdd(&counts[s], 1) & 63;  // P(deg>=64) ~ 1e-18 for Poisson(16)
    elist[s*64 + pos] = e;
  }
}

// ---------------- node aggregation (one wave per node) ----------------
// node_agg layout: [node][n(64)][k(16)] -> contiguous 16 floats per lane
__global__ __launch_bounds__(256) void k_node(
    const float* __restrict__ vec, const float* __restrict__ w_ws,
    const int* __restrict__ counts, const int* __restrict__ elist,
    float* __restrict__ node_agg)
{
  const int wid = threadIdx.x >> 6, lane = threadIdx.x & 63;
  const int s = blockIdx.x * 4 + wid;
  const int deg = min(counts[s], 64);

  const float S3 = 1.7320508075688772f, S5 = 2.23606797749979f, S15 = 3.872983346207417f;
  const float C33 = 2.091650066335189f, C32 = 5.123475382979799f, C31 = 1.6201851746019651f;
  const float C30 = 1.3228756555322954f, CX = 10.246950765959598f;

  float A[16];
  #pragma unroll
  for (int k = 0; k < 16; k++) A[k] = 0.f;

  for (int ii = 0; ii < deg; ii++) {
    int e = elist[s*64 + ii];
    float vx = vec[e*3+0], vy = vec[e*3+1], vz = vec[e*3+2];
    float d = sqrtf(vx*vx + vy*vy + vz*vz);
    float X = vx/d, Yv = vy/d, Z = vz/d;
    float y[16];
    y[0] = 1.f;
    y[1] = S3*X;  y[2] = S3*Yv;  y[3] = S3*Z;
    y[4] = S15*X*Yv; y[5] = S15*Yv*Z; y[6] = 0.5f*S5*(3.f*Z*Z - 1.f);
    y[7] = S15*X*Z;  y[8] = 0.5f*S15*(X*X - Yv*Yv);
    y[9]  = C33*Yv*(3.f*X*X - Yv*Yv);
    y[10] = CX*X*Yv*Z;
    y[11] = C31*Yv*(5.f*Z*Z - 1.f);
    y[12] = C30*Z*(5.f*Z*Z - 3.f);
    y[13] = C31*X*(5.f*Z*Z - 1.f);
    y[14] = C32*Z*(X*X - Yv*Yv);
    y[15] = C33*X*(X*X - 3.f*Yv*Yv);
    float wv = w_ws[e*64 + lane];
    #pragma unroll
    for (int k = 0; k < 16; k++) A[k] = fmaf(wv, y[k], A[k]);
  }
  float* dst = node_agg + s*1024 + lane*16;
  #pragma unroll
  for (int k = 0; k < 4; k++)
    ((f32x4*)dst)[k] = (f32x4){A[4*k], A[4*k+1], A[4*k+2], A[4*k+3]};
}

// ---------------- TP helper (fully unrolled; cg reads are wave-uniform -> s_load) ----------------
template<int L1, int L2, int L3>
__device__ __forceinline__ void tp_path(const float* __restrict__ cgp,
    const float a[16], const float b[9], float o[2*L3+1])
{
  constexpr int N1 = 2*L1+1, N2 = 2*L2+1, N3 = 2*L3+1;
  constexpr int AO = (L1==0) ? 0 : (L1==1) ? 1 : (L1==2) ? 4 : 9;
  constexpr int BO = (L2==0) ? 0 : (L2==1) ? 1 : 4;
  #pragma unroll
  for (int k = 0; k < N3; k++) o[k] = 0.f;
  int ci = 0;
  #pragma unroll
  for (int i = 0; i < N1; i++) {
    #pragma unroll
    for (int j = 0; j < N2; j++) {
      float ab = a[AO+i] * b[BO+j];
      #pragma unroll
      for (int k = 0; k < N3; k++) { o[k] = fmaf(ab, cgp[ci], o[k]); ci++; }
    }
  }
}

// ---------------- main fused kernel: TP -> MFMA GEMMs -> outputs ----------------
// EB=4 edges/block, one edge per wave. LDS ~34.3KB -> 4 blocks/CU.
__global__ __launch_bounds__(256, 4) void edge_main(
    const float* __restrict__ vec, const float* __restrict__ x,
    const float* __restrict__ V, const int* __restrict__ senders,
    const float* __restrict__ node_agg, const float* __restrict__ cg,
    const unsigned short* __restrict__ wv1f, const unsigned short* __restrict__ wv2f,
    const unsigned short* __restrict__ w1f, const unsigned short* __restrict__ w2f,
    const unsigned short* __restrict__ w3f,
    float* __restrict__ out, int E, const float* __restrict__ actp)
{
  __shared__ __align__(16) unsigned short V1sh[12*328];  // rows (eloc*3+i), K=320
  __shared__ __align__(16) unsigned short V2sh[20*328];  // rows (eloc*5+i), K=320
  __shared__ __align__(16) unsigned short zrow[336];     // zero row for M-tile padding
  __shared__ __align__(16) unsigned short hsh[4*264];    // rows=edges, K=256 = [x(64)|scal(192)]
  __shared__ __align__(16) unsigned short h1sh[4*72];
  __shared__ __align__(16) unsigned short h2sh[4*72];
  __shared__ __align__(16) float vosh[4*584];            // staged V_out, 576 floats/edge
  __shared__ float ush[EB];

  const int t = threadIdx.x;
  const int wid = t >> 6, lane = t & 63;
  const int e0 = blockIdx.x * EB;
  const size_t E64 = (size_t)E * 64;
  const float inv_actc = 1.f / sqrtf((actp[0]+actp[1]+actp[2]+actp[3]
                                     +actp[4]+actp[5]+actp[6]+actp[7]) * (24.0f/200000.0f));

  if (t < 168) ((unsigned int*)zrow)[t] = 0u;

  // x -> hsh[:, 0:64]
  { int el = t >> 6, o = t & 63;
    hsh[el*264 + o] = f2bf(x[(e0+el)*64 + o]); }

  // ---- TP phase: one edge per wave ----
  {
    const int eloc = wid;
    const int eg = e0 + eloc;
    const int s = senders[eg];

    float a[16];
    const float* nap = node_agg + s*1024 + lane*16;
    #pragma unroll
    for (int k = 0; k < 16; k++) a[k] = nap[k] * 0.25f;

    // V[e][n=lane][j] : 9 contiguous dwords per lane
    float b[9];
    const float* vp = V + (size_t)eg*576 + lane*9;
    #pragma unroll
    for (int j = 0; j < 9; j++) b[j] = vp[j];

    float o1[1], o3[3], o5[5];
    // scal paths -> hsh cols 64 + lane*3 + p
    tp_path<0,0,0>(cg + 0,  a, b, o1); hsh[eloc*264 + 64 + lane*3 + 0] = f2bf(o1[0]);
    tp_path<1,1,0>(cg + 1,  a, b, o1); hsh[eloc*264 + 64 + lane*3 + 1] = f2bf(o1[0]);
    tp_path<2,2,0>(cg + 10, a, b, o1); hsh[eloc*264 + 64 + lane*3 + 2] = f2bf(o1[0]);
    // V1 paths (K index = pb*64 + lane)
    tp_path<0,1,1>(cg + 35, a, b, o3);
    { int r = eloc*3; for (int i=0;i<3;i++) V1sh[(r+i)*328 + 0*64 + lane] = f2bf(o3[i]); }
    tp_path<1,0,1>(cg + 44, a, b, o3);
    { int r = eloc*3; for (int i=0;i<3;i++) V1sh[(r+i)*328 + 1*64 + lane] = f2bf(o3[i]); }
    tp_path<1,2,1>(cg + 53, a, b, o3);
    { int r = eloc*3; for (int i=0;i<3;i++) V1sh[(r+i)*328 + 2*64 + lane] = f2bf(o3[i]); }
    tp_path<2,1,1>(cg + 98, a, b, o3);
    { int r = eloc*3; for (int i=0;i<3;i++) V1sh[(r+i)*328 + 3*64 + lane] = f2bf(o3[i]); }
    tp_path<3,2,1>(cg + 143, a, b, o3);
    { int r = eloc*3; for (int i=0;i<3;i++) V1sh[(r+i)*328 + 4*64 + lane] = f2bf(o3[i]); }
    // V2 paths
    tp_path<0,2,2>(cg + 248, a, b, o5);
    { int r = eloc*5; for (int i=0;i<5;i++) V2sh[(r+i)*328 + 0*64 + lane] = f2bf(o5[i]); }
    tp_path<1,1,2>(cg + 273, a, b, o5);
    { int r = eloc*5; for (int i=0;i<5;i++) V2sh[(r+i)*328 + 1*64 + lane] = f2bf(o5[i]); }
    tp_path<2,0,2>(cg + 318, a, b, o5);
    { int r = eloc*5; for (int i=0;i<5;i++) V2sh[(r+i)*328 + 2*64 + lane] = f2bf(o5[i]); }
    tp_path<2,2,2>(cg + 343, a, b, o5);
    { int r = eloc*5; for (int i=0;i<5;i++) V2sh[(r+i)*328 + 3*64 + lane] = f2bf(o5[i]); }
    tp_path<3,1,2>(cg + 468, a, b, o5);
    { int r = eloc*5; for (int i=0;i<5;i++) V2sh[(r+i)*328 + 4*64 + lane] = f2bf(o5[i]); }

    if (lane == 0) {
      float vx = vec[eg*3+0], vy = vec[eg*3+1], vz = vec[eg*3+2];
      float d = sqrtf(vx*vx + vy*vy + vz*vz);
      float u = 0.f;
      if (d < 1.f) {
        float d3 = d*d*d, d6 = d3*d3, d7 = d6*d, d8 = d7*d;
        u = 1.f - 28.f*d6 + 48.f*d7 - 21.f*d8;
      }
      ush[eloc] = u;
    }
  }
  __syncthreads();

  // ---- MFMA GEMM phase: wave wid owns output-column tile ntile=wid (16 cols) ----
  const int ntile = wid;
  const int qr = lane >> 4;
  const int ml = lane & 15;
  const float s320 = 0.05590169943749474f;  // 1/sqrt(320)

  // V1: M=12 (1 tile), K=320 -> vosh
  {
    f32x4 acc = (f32x4){0,0,0,0};
    const unsigned short* p0 = (ml < 12) ? &V1sh[ml*328] : zrow;
    const unsigned short* bb = wv1f + ((size_t)(ntile*10)*64 + lane)*8;
    #pragma unroll
    for (int ks = 0; ks < 10; ks++) {
      short8 bf = *(const short8*)(bb + ks*512);
      short8 af = *(const short8*)(p0 + ks*32 + qr*8);
      acc = __builtin_amdgcn_mfma_f32_16x16x32_bf16(af, bf, acc, 0, 0, 0);
    }
    #pragma unroll
    for (int r = 0; r < 4; r++) {
      int row = qr*4 + r;
      if (row < 12) {
        int el = row / 3, i = row - (row/3)*3;
        vosh[el*584 + (ntile*16+ml)*9 + 1 + i] = acc[r] * s320;
      }
    }
  }

  // V2: M=20 (2 tiles), K=320 -> vosh
  {
    f32x4 acc[2]; acc[0] = (f32x4){0,0,0,0}; acc[1] = (f32x4){0,0,0,0};
    const unsigned short* p0 = &V2sh[ml*328];
    const unsigned short* p1 = (16+ml < 20) ? &V2sh[(16+ml)*328] : zrow;
    const unsigned short* bb = wv2f + ((size_t)(ntile*10)*64 + lane)*8;
    #pragma unroll
    for (int ks = 0; ks < 10; ks++) {
      short8 bf = *(const short8*)(bb + ks*512);
      int ao = ks*32 + qr*8;
      short8 af0 = *(const short8*)(p0 + ao);
      short8 af1 = *(const short8*)(p1 + ao);
      acc[0] = __builtin_amdgcn_mfma_f32_16x16x32_bf16(af0, bf, acc[0], 0, 0, 0);
      acc[1] = __builtin_amdgcn_mfma_f32_16x16x32_bf16(af1, bf, acc[1], 0, 0, 0);
    }
    #pragma unroll
    for (int mt = 0; mt < 2; mt++) {
      #pragma unroll
      for (int r = 0; r < 4; r++) {
        int row = mt*16 + qr*4 + r;
        if (row < 20) {
          int el = row / 5, i = row - (row/5)*5;
          vosh[el*584 + (ntile*16+ml)*9 + 4 + i] = acc[mt][r] * s320;
        }
      }
    }
  }

  // V_out channel 0 = 0
  { int el = t >> 6, o = t & 63;
    vosh[el*584 + o*9] = 0.f; }

  // ---- MLP via MFMA (M=4 real rows padded to 16) ----
  const unsigned short* hp = (ml < 4) ? &hsh[ml*264] : zrow;
  {
    f32x4 c = (f32x4){0,0,0,0};
    const unsigned short* bb = w1f + ((size_t)(ntile*8)*64 + lane)*8;
    #pragma unroll
    for (int ks = 0; ks < 8; ks++) {
      short8 bf = *(const short8*)(bb + ks*512);
      short8 af = *(const short8*)(hp + ks*32 + qr*8);
      c = __builtin_amdgcn_mfma_f32_16x16x32_bf16(af, bf, c, 0, 0, 0);
    }
    #pragma unroll
    for (int r = 0; r < 4; r++) {
      int row = qr*4 + r;
      if (row < 4) {
        float v = c[r] * 0.0625f;
        float sv = v / (1.f + expf(-v)) * inv_actc;
        h1sh[row*72 + ntile*16 + ml] = f2bf(sv);
      }
    }
  }
  __syncthreads();
  {
    f32x4 c = (f32x4){0,0,0,0};
    const unsigned short* ap = (ml < 4) ? &h1sh[ml*72] : zrow;
    const unsigned short* bb = w2f + ((size_t)(ntile*2)*64 + lane)*8;
    #pragma unroll
    for (int ks = 0; ks < 2; ks++) {
      short8 bf = *(const short8*)(bb + ks*512);
      short8 af = *(const short8*)(ap + ks*32 + qr*8);
      c = __builtin_amdgcn_mfma_f32_16x16x32_bf16(af, bf, c, 0, 0, 0);
    }
    #pragma unroll
    for (int r = 0; r < 4; r++) {
      int row = qr*4 + r;
      if (row < 4) {
        float v = c[r] * 0.125f;
        float sv = v / (1.f + expf(-v)) * inv_actc;
        h2sh[row*72 + ntile*16 + ml] = f2bf(sv);
      }
    }
  }
  __syncthreads();
  {
    f32x4 c = (f32x4){0,0,0,0};
    const unsigned short* ap = (ml < 4) ? &h2sh[ml*72] : zrow;
    const unsigned short* bb = w3f + ((size_t)(ntile*2)*64 + lane)*8;
    #pragma unroll
    for (int ks = 0; ks < 2; ks++) {
      short8 bf = *(const short8*)(bb + ks*512);
      short8 af = *(const short8*)(ap + ks*32 + qr*8);
      c = __builtin_amdgcn_mfma_f32_16x16x32_bf16(af, bf, c, 0, 0, 0);
    }
    #pragma unroll
    for (int r = 0; r < 4; r++) {
      int row = qr*4 + r;
      if (row < 4) {
        float v = c[r] * 0.125f;
        out[(size_t)(e0+row)*64 + ntile*16 + ml] = ush[row] * v;
      }
    }
  }

  // coalesced float4 store of staged V_out
  for (int q = t; q < 576; q += 256) {
    int el = q / 144, i4 = q - (q/144)*144;
    ((f32x4*)(out + E64 + (size_t)(e0+el)*576))[i4] = ((f32x4*)(vosh + el*584))[i4];
  }
}

extern "C" void kernel_launch(void* const* d_in, const int* in_sizes, int n_in,
                              void* d_out, int out_size, void* d_ws, size_t ws_size,
                              hipStream_t stream)
{
  const float* vec     = (const float*)d_in[0];
  const float* x       = (const float*)d_in[1];
  const float* V       = (const float*)d_in[2];
  const int*   senders = (const int*)  d_in[3];
  const float* Ww      = (const float*)d_in[4];
  const float* W1      = (const float*)d_in[5];
  const float* W2      = (const float*)d_in[6];
  const float* W3      = (const float*)d_in[7];
  const float* Wv1     = (const float*)d_in[8];
  const float* Wv2     = (const float*)d_in[9];
  float* out = (float*)d_out;
  const int E = in_sizes[0] / 3;

  // ---- workspace layout ----
  char* base = (char*)d_ws;
  float* node_agg = (float*)(base);                        // 4 MB  [node][n][k]
  float* w_ws     = (float*)(base + (4<<20));              // 4 MB
  float* cg       = (float*)(base + (8<<20));              // 573 floats
  float* actp     = (float*)(base + (8<<20) + 4096);       // 8 floats
  int* counts     = (int*)  (base + (8<<20) + 8192);       // 1024 ints
  int* elist      = (int*)  (base + (8<<20) + 12288);      // 1024*64 ints = 256 KB
  unsigned short* wv1f = (unsigned short*)(base + (8<<20) + 278528);  // 40 KB
  unsigned short* wv2f = (unsigned short*)(base + (8<<20) + 319488);  // 40 KB
  unsigned short* w1f  = (unsigned short*)(base + (8<<20) + 360448);  // 32 KB
  unsigned short* w2f  = (unsigned short*)(base + (8<<20) + 393216);  // 8 KB
  unsigned short* w3f  = (unsigned short*)(base + (8<<20) + 401408);  // 8 KB

  k0<<<4, 256, 0, stream>>>(counts);
  prep<<<53, 256, 0, stream>>>(Wv1, Wv2, W1, W2, W3,
                               wv1f, wv2f, w1f, w2f, w3f, cg, actp);
  edgepass<<<(E+3)/4, 256, 0, stream>>>(x, Ww, senders, w_ws, counts, elist, E);
  k_node<<<NNODES/4, 256, 0, stream>>>(vec, w_ws, counts, elist, node_agg);
  edge_main<<<E/EB, 256, 0, stream>>>(vec, x, V, senders, node_agg, cg,
                                      wv1f, wv2f, w1f, w2f, w3f, out, E, actp);
}

// Round 7
// 169.178 us; speedup vs baseline: 1.1114x; 1.1114x over previous
//
#include <hip/hip_runtime.h>
#include <math.h>

#define NNODES 1024
#define EDGES 16384
#define EB 4   // edges per block in edge_main (one edge per wave)

typedef __attribute__((ext_vector_type(8))) short short8;
typedef __attribute__((ext_vector_type(4))) float f32x4;

__device__ __forceinline__ unsigned short f2bf(float f) {
  union { float f; unsigned int u; } v; v.f = f;
  unsigned int r = v.u + 0x7fffu + ((v.u >> 16) & 1u);
  return (unsigned short)(r >> 16);
}

// ---------------- path tables ----------------
__device__ __constant__ int PL1[13] = {0,1,2, 0,1,1,2,3, 0,1,2,2,3};
__device__ __constant__ int PL2[13] = {0,1,2, 1,0,2,1,2, 2,1,0,2,1};
__device__ __constant__ int PL3[13] = {0,0,0, 1,1,1,1,1, 2,2,2,2,2};
__device__ __constant__ int PCG[13] = {0,1,10, 35,44,53,98,143, 248,273,318,343,468};

// ---------------- SH polynomial tables (2 terms max per lm; coeff 0 = absent) ----
__device__ __constant__ double SHC[16][2] = {
  {1.0, 0.0},
  {1.7320508075688772, 0.0},
  {1.7320508075688772, 0.0},
  {1.7320508075688772, 0.0},
  {3.8729833462074170, 0.0},
  {3.8729833462074170, 0.0},
  {3.3541019662496844, -1.1180339887498949},
  {3.8729833462074170, 0.0},
  {1.9364916731037085, -1.9364916731037085},
  {6.2749501990055667, -2.0916500663351889},
  {10.246950765959598, 0.0},
  {8.1009258730098255, -1.6201851746019651},
  {6.6143782776614768, -3.9686269665968861},
  {8.1009258730098255, -1.6201851746019651},
  {5.1234753829797990, -5.1234753829797990},
  {2.0916500663351889, -6.2749501990055667},
};
// exponents packed ex | ey<<4 | ez<<8
__device__ __constant__ int SHE[16][2] = {
  {0,0},{1,0},{16,0},{256,0},
  {17,0},{272,0},{512,0},{257,0},{2,32},
  {18,48},{273,0},{528,16},{768,256},{513,1},{258,288},{3,33}};

// ---------------- prep: CG+zero counts (b0-12) + ACT partials (b13-20) + pack (b21-52) ----
__global__ __launch_bounds__(256) void prep(
    const float* __restrict__ Wv1, const float* __restrict__ Wv2,
    const float* __restrict__ W1, const float* __restrict__ W2, const float* __restrict__ W3,
    unsigned short* __restrict__ wv1f, unsigned short* __restrict__ wv2f,
    unsigned short* __restrict__ w1f, unsigned short* __restrict__ w2f,
    unsigned short* __restrict__ w3f,
    float* __restrict__ cg, float* __restrict__ actp, int* __restrict__ counts)
{
  const int bid = blockIdx.x;
  const int t = threadIdx.x;

  if (bid < 13) {
    if (bid < 4) counts[bid*256 + t] = 0;
    // ---- CG tensor for path bid: scratch-free, fully unrolled ----
    __shared__ double sh[256];
    const int p = bid;
    const int LOFF[4] = {0,1,4,9};
    int l1 = PL1[p], l2 = PL2[p], l3 = PL3[p];
    int n1 = 2*l1+1, n2 = 2*l2+1, n3 = 2*l3+1;
    int nent = n1*n2*n3;
    // df(n-1) for n=0..8, 7 bits each: {1,1,1,2,3,8,15,48,105}
    const unsigned long long DP =
        1ULL | (1ULL<<7) | (1ULL<<14) | (2ULL<<21) | (3ULL<<28)
      | (8ULL<<35) | (15ULL<<42) | (48ULL<<49) | (105ULL<<56);
    double v = 0.0;
    if (t < nent) {
      int i = t / (n2*n3);
      int rem = t - i*(n2*n3);
      int j = rem / n3;
      int k = rem - j*n3;
      int lm1 = LOFF[l1]+i, lm2 = LOFF[l2]+j, lm3 = LOFF[l3]+k;
      double cs1[2] = {SHC[lm1][0], SHC[lm1][1]}; int es1[2] = {SHE[lm1][0], SHE[lm1][1]};
      double cs2[2] = {SHC[lm2][0], SHC[lm2][1]}; int es2[2] = {SHE[lm2][0], SHE[lm2][1]};
      double cs3[2] = {SHC[lm3][0], SHC[lm3][1]}; int es3[2] = {SHE[lm3][0], SHE[lm3][1]};
      #pragma unroll
      for (int t1 = 0; t1 < 2; t1++)
      #pragma unroll
      for (int t2 = 0; t2 < 2; t2++)
      #pragma unroll
      for (int t3 = 0; t3 < 2; t3++) {
        double cc = cs1[t1]*cs2[t2]*cs3[t3];
        int s = es1[t1] + es2[t2] + es3[t3];   // nibble sums, no carries
        int a = s & 15, b = (s >> 4) & 15, c = (s >> 8) & 15;
        if (!((a|b|c) & 1)) {
          double num = (double)(int)((DP >> (7*a)) & 127)
                     * (double)(int)((DP >> (7*b)) & 127)
                     * (double)(int)((DP >> (7*c)) & 127);
          double den = (double)(int)((DP >> (7*(a+b+c+2))) & 127);
          v += cc * (num / den);
        }
      }
    }
    sh[t] = (t < nent) ? v*v : 0.0;
    __syncthreads();
    for (int d = 128; d > 0; d >>= 1) {
      if (t < d) sh[t] += sh[t+d];
      __syncthreads();
    }
    double scale = sqrt((double)(2*l3+1)) / sqrt(sh[0]);
    if (t < nent) cg[PCG[p] + t] = (float)(v * scale);

  } else if (bid < 21) {
    // ---- ACT_C partial sums ----
    __shared__ float shf[256];
    const int b = bid - 13;
    const float dz = 24.0f / 200000.0f;
    float s = 0.f;
    for (int i = b*256 + t; i <= 200000; i += 8*256) {
      float z = -12.0f + dz * (float)i;
      float ph = __expf(-0.5f * z * z) * 0.3989422804014327f;
      float sl = z / (1.f + __expf(-z));
      s = fmaf(sl*sl, ph, s);
    }
    shf[t] = s;
    __syncthreads();
    for (int d = 128; d > 0; d >>= 1) {
      if (t < d) shf[t] += shf[t + d];
      __syncthreads();
    }
    if (t == 0) actp[b] = shf[0];

  } else {
    // ---- weight fragment pack: 4 fragments per block ----
    const int wid = t >> 6, lane = t & 63;
    const int g = (bid - 21)*4 + wid;
    const float* src; unsigned short* dst; int nk, f;
    if (g < 40)       { src = Wv1; dst = wv1f; nk = 10; f = g; }
    else if (g < 80)  { src = Wv2; dst = wv2f; nk = 10; f = g - 40; }
    else if (g < 112) { src = W1;  dst = w1f;  nk = 8;  f = g - 80; }
    else if (g < 120) { src = W2;  dst = w2f;  nk = 2;  f = g - 112; }
    else              { src = W3;  dst = w3f;  nk = 2;  f = g - 120; }
    int nt = f / nk;
    int ks = f - nt*nk;
    unsigned short us[8];
    #pragma unroll
    for (int j = 0; j < 8; j++) {
      float v = src[(ks*32 + (lane>>4)*8 + j)*64 + nt*16 + (lane & 15)];
      us[j] = f2bf(v);
    }
    uint4 pk;
    pk.x = (unsigned)us[0] | ((unsigned)us[1] << 16);
    pk.y = (unsigned)us[2] | ((unsigned)us[3] << 16);
    pk.z = (unsigned)us[4] | ((unsigned)us[5] << 16);
    pk.w = (unsigned)us[6] | ((unsigned)us[7] << 16);
    *(uint4*)(dst + ((size_t)f*64 + lane)*8) = pk;
  }
}

// ---------------- edgepass: w = x @ W_w / 8, plus bucket scatter ----------------
__global__ __launch_bounds__(256) void edgepass(
    const float* __restrict__ x, const float* __restrict__ Ww,
    const int* __restrict__ senders,
    float* __restrict__ w_ws, int* __restrict__ counts, int* __restrict__ elist, int E)
{
  const int wid = threadIdx.x >> 6, lane = threadIdx.x & 63;
  const int e = blockIdx.x * 4 + wid;
  if (e >= E) return;
  float xv = x[e*64 + lane];
  float w = 0.f;
  #pragma unroll
  for (int f = 0; f < 64; f++)
    w = fmaf(__shfl(xv, f), Ww[f*64 + lane], w);
  w_ws[e*64 + lane] = w * 0.125f;
  if (lane == 0) {
    int s = senders[e];
    int pos = atomicAdd(&counts[s], 1) & 63;  // P(deg>=64) ~ 1e-18 for Poisson(16)
    elist[s*64 + pos] = e;
  }
}

// ---------------- node aggregation (one BLOCK per node, 4 waves split edges) ----
// node_agg layout: [node][n(64)][k(16)] -> contiguous 16 floats per lane
__global__ __launch_bounds__(256) void k_node(
    const float* __restrict__ vec, const float* __restrict__ w_ws,
    const int* __restrict__ counts, const int* __restrict__ elist,
    float* __restrict__ node_agg)
{
  __shared__ float red[4*1024];
  const int wid = threadIdx.x >> 6, lane = threadIdx.x & 63;
  const int s = blockIdx.x;
  const int deg = min(counts[s], 64);

  const float S3 = 1.7320508075688772f, S5 = 2.23606797749979f, S15 = 3.872983346207417f;
  const float C33 = 2.091650066335189f, C32 = 5.123475382979799f, C31 = 1.6201851746019651f;
  const float C30 = 1.3228756555322954f, CX = 10.246950765959598f;

  float A[16];
  #pragma unroll
  for (int k = 0; k < 16; k++) A[k] = 0.f;

  for (int ii = wid; ii < deg; ii += 4) {
    int e = elist[s*64 + ii];
    float vx = vec[e*3+0], vy = vec[e*3+1], vz = vec[e*3+2];
    float d = sqrtf(vx*vx + vy*vy + vz*vz);
    float X = vx/d, Yv = vy/d, Z = vz/d;
    float y[16];
    y[0] = 1.f;
    y[1] = S3*X;  y[2] = S3*Yv;  y[3] = S3*Z;
    y[4] = S15*X*Yv; y[5] = S15*Yv*Z; y[6] = 0.5f*S5*(3.f*Z*Z - 1.f);
    y[7] = S15*X*Z;  y[8] = 0.5f*S15*(X*X - Yv*Yv);
    y[9]  = C33*Yv*(3.f*X*X - Yv*Yv);
    y[10] = CX*X*Yv*Z;
    y[11] = C31*Yv*(5.f*Z*Z - 1.f);
    y[12] = C30*Z*(5.f*Z*Z - 3.f);
    y[13] = C31*X*(5.f*Z*Z - 1.f);
    y[14] = C32*Z*(X*X - Yv*Yv);
    y[15] = C33*X*(X*X - 3.f*Yv*Yv);
    float wv = w_ws[e*64 + lane];
    #pragma unroll
    for (int k = 0; k < 16; k++) A[k] = fmaf(wv, y[k], A[k]);
  }
  #pragma unroll
  for (int k = 0; k < 16; k++) red[wid*1024 + lane*16 + k] = A[k];
  __syncthreads();
  // 256 threads x 4 consecutive floats each
  const int t = threadIdx.x;
  f32x4 v0 = ((f32x4*)red)[t];
  f32x4 v1 = ((f32x4*)red)[256 + t];
  f32x4 v2 = ((f32x4*)red)[512 + t];
  f32x4 v3 = ((f32x4*)red)[768 + t];
  f32x4 sum = v0 + v1 + v2 + v3;
  ((f32x4*)(node_agg + (size_t)s*1024))[t] = sum;
}

// ---------------- TP helper: fully unrolled with compile-time parity masking ----
// PAR[lm] = monomial parity (bit0=x, bit1=y, bit2=z); entry (i,j,k) can be
// nonzero only if parities XOR to 0. Masked-out entries have cg==0 anyway.
template<int L1, int L2, int L3>
__device__ __forceinline__ void tp_path(const float* __restrict__ cgp,
    const float a[16], const float b[9], float o[2*L3+1])
{
  constexpr int N1 = 2*L1+1, N2 = 2*L2+1, N3 = 2*L3+1;
  constexpr int AO = (L1==0) ? 0 : (L1==1) ? 1 : (L1==2) ? 4 : 9;
  constexpr int BO = (L2==0) ? 0 : (L2==1) ? 1 : 4;
  constexpr int LM1 = (L1==0) ? 0 : (L1==1) ? 1 : (L1==2) ? 4 : 9;
  constexpr int LM2 = (L2==0) ? 0 : (L2==1) ? 1 : 4;
  constexpr int LM3 = (L3==0) ? 0 : (L3==1) ? 1 : 4;
  static constexpr unsigned char PAR[16] =
      {0, 1,2,4, 3,6,0,5,0, 2,7,2,4,1,4,1};
  #pragma unroll
  for (int k = 0; k < N3; k++) o[k] = 0.f;
  int ci = 0;
  #pragma unroll
  for (int i = 0; i < N1; i++) {
    #pragma unroll
    for (int j = 0; j < N2; j++) {
      float ab = a[AO+i] * b[BO+j];
      #pragma unroll
      for (int k = 0; k < N3; k++) {
        if ((PAR[LM1+i] ^ PAR[LM2+j] ^ PAR[LM3+k]) == 0)
          o[k] = fmaf(ab, cgp[ci], o[k]);
        ci++;
      }
    }
  }
}

// ---------------- main fused kernel: TP -> MFMA GEMMs -> outputs ----------------
__global__ __launch_bounds__(256, 4) void edge_main(
    const float* __restrict__ vec, const float* __restrict__ x,
    const float* __restrict__ V, const int* __restrict__ senders,
    const float* __restrict__ node_agg, const float* __restrict__ cg,
    const unsigned short* __restrict__ wv1f, const unsigned short* __restrict__ wv2f,
    const unsigned short* __restrict__ w1f, const unsigned short* __restrict__ w2f,
    const unsigned short* __restrict__ w3f,
    float* __restrict__ out, int E, const float* __restrict__ actp)
{
  __shared__ __align__(16) unsigned short V1sh[12*328];
  __shared__ __align__(16) unsigned short V2sh[20*328];
  __shared__ __align__(16) unsigned short zrow[336];
  __shared__ __align__(16) unsigned short hsh[4*264];
  __shared__ __align__(16) unsigned short h1sh[4*72];
  __shared__ __align__(16) unsigned short h2sh[4*72];
  __shared__ __align__(16) float vosh[4*584];
  __shared__ float ush[EB];

  const int t = threadIdx.x;
  const int wid = t >> 6, lane = t & 63;
  const int e0 = blockIdx.x * EB;
  const size_t E64 = (size_t)E * 64;
  const float inv_actc = 1.f / sqrtf((actp[0]+actp[1]+actp[2]+actp[3]
                                     +actp[4]+actp[5]+actp[6]+actp[7]) * (24.0f/200000.0f));

  if (t < 168) ((unsigned int*)zrow)[t] = 0u;

  { int el = t >> 6, o = t & 63;
    hsh[el*264 + o] = f2bf(x[(e0+el)*64 + o]); }

  // ---- TP phase: one edge per wave ----
  {
    const int eloc = wid;
    const int eg = e0 + eloc;
    const int s = senders[eg];

    float a[16];
    const float* nap = node_agg + s*1024 + lane*16;
    #pragma unroll
    for (int k = 0; k < 16; k++) a[k] = nap[k] * 0.25f;

    float b[9];
    const float* vp = V + (size_t)eg*576 + lane*9;
    #pragma unroll
    for (int j = 0; j < 9; j++) b[j] = vp[j];

    float o1[1], o3[3], o5[5];
    tp_path<0,0,0>(cg + 0,  a, b, o1); hsh[eloc*264 + 64 + lane*3 + 0] = f2bf(o1[0]);
    tp_path<1,1,0>(cg + 1,  a, b, o1); hsh[eloc*264 + 64 + lane*3 + 1] = f2bf(o1[0]);
    tp_path<2,2,0>(cg + 10, a, b, o1); hsh[eloc*264 + 64 + lane*3 + 2] = f2bf(o1[0]);
    tp_path<0,1,1>(cg + 35, a, b, o3);
    { int r = eloc*3; for (int i=0;i<3;i++) V1sh[(r+i)*328 + 0*64 + lane] = f2bf(o3[i]); }
    tp_path<1,0,1>(cg + 44, a, b, o3);
    { int r = eloc*3; for (int i=0;i<3;i++) V1sh[(r+i)*328 + 1*64 + lane] = f2bf(o3[i]); }
    tp_path<1,2,1>(cg + 53, a, b, o3);
    { int r = eloc*3; for (int i=0;i<3;i++) V1sh[(r+i)*328 + 2*64 + lane] = f2bf(o3[i]); }
    tp_path<2,1,1>(cg + 98, a, b, o3);
    { int r = eloc*3; for (int i=0;i<3;i++) V1sh[(r+i)*328 + 3*64 + lane] = f2bf(o3[i]); }
    tp_path<3,2,1>(cg + 143, a, b, o3);
    { int r = eloc*3; for (int i=0;i<3;i++) V1sh[(r+i)*328 + 4*64 + lane] = f2bf(o3[i]); }
    tp_path<0,2,2>(cg + 248, a, b, o5);
    { int r = eloc*5; for (int i=0;i<5;i++) V2sh[(r+i)*328 + 0*64 + lane] = f2bf(o5[i]); }
    tp_path<1,1,2>(cg + 273, a, b, o5);
    { int r = eloc*5; for (int i=0;i<5;i++) V2sh[(r+i)*328 + 1*64 + lane] = f2bf(o5[i]); }
    tp_path<2,0,2>(cg + 318, a, b, o5);
    { int r = eloc*5; for (int i=0;i<5;i++) V2sh[(r+i)*328 + 2*64 + lane] = f2bf(o5[i]); }
    tp_path<2,2,2>(cg + 343, a, b, o5);
    { int r = eloc*5; for (int i=0;i<5;i++) V2sh[(r+i)*328 + 3*64 + lane] = f2bf(o5[i]); }
    tp_path<3,1,2>(cg + 468, a, b, o5);
    { int r = eloc*5; for (int i=0;i<5;i++) V2sh[(r+i)*328 + 4*64 + lane] = f2bf(o5[i]); }

    if (lane == 0) {
      float vx = vec[eg*3+0], vy = vec[eg*3+1], vz = vec[eg*3+2];
      float d = sqrtf(vx*vx + vy*vy + vz*vz);
      float u = 0.f;
      if (d < 1.f) {
        float d3 = d*d*d, d6 = d3*d3, d7 = d6*d, d8 = d7*d;
        u = 1.f - 28.f*d6 + 48.f*d7 - 21.f*d8;
      }
      ush[eloc] = u;
    }
  }
  __syncthreads();

  // ---- MFMA GEMM phase: wave wid owns output-column tile ntile=wid (16 cols) ----
  const int ntile = wid;
  const int qr = lane >> 4;
  const int ml = lane & 15;
  const float s320 = 0.05590169943749474f;  // 1/sqrt(320)

  // V1: M=12 (1 tile), K=320 -> vosh
  {
    f32x4 acc = (f32x4){0,0,0,0};
    const unsigned short* p0 = (ml < 12) ? &V1sh[ml*328] : zrow;
    const unsigned short* bb = wv1f + ((size_t)(ntile*10)*64 + lane)*8;
    #pragma unroll
    for (int ks = 0; ks < 10; ks++) {
      short8 bf = *(const short8*)(bb + ks*512);
      short8 af = *(const short8*)(p0 + ks*32 + qr*8);
      acc = __builtin_amdgcn_mfma_f32_16x16x32_bf16(af, bf, acc, 0, 0, 0);
    }
    #pragma unroll
    for (int r = 0; r < 4; r++) {
      int row = qr*4 + r;
      if (row < 12) {
        int el = row / 3, i = row - (row/3)*3;
        vosh[el*584 + (ntile*16+ml)*9 + 1 + i] = acc[r] * s320;
      }
    }
  }

  // V2: M=20 (2 tiles), K=320 -> vosh
  {
    f32x4 acc[2]; acc[0] = (f32x4){0,0,0,0}; acc[1] = (f32x4){0,0,0,0};
    const unsigned short* p0 = &V2sh[ml*328];
    const unsigned short* p1 = (16+ml < 20) ? &V2sh[(16+ml)*328] : zrow;
    const unsigned short* bb = wv2f + ((size_t)(ntile*10)*64 + lane)*8;
    #pragma unroll
    for (int ks = 0; ks < 10; ks++) {
      short8 bf = *(const short8*)(bb + ks*512);
      int ao = ks*32 + qr*8;
      short8 af0 = *(const short8*)(p0 + ao);
      short8 af1 = *(const short8*)(p1 + ao);
      acc[0] = __builtin_amdgcn_mfma_f32_16x16x32_bf16(af0, bf, acc[0], 0, 0, 0);
      acc[1] = __builtin_amdgcn_mfma_f32_16x16x32_bf16(af1, bf, acc[1], 0, 0, 0);
    }
    #pragma unroll
    for (int mt = 0; mt < 2; mt++) {
      #pragma unroll
      for (int r = 0; r < 4; r++) {
        int row = mt*16 + qr*4 + r;
        if (row < 20) {
          int el = row / 5, i = row - (row/5)*5;
          vosh[el*584 + (ntile*16+ml)*9 + 4 + i] = acc[mt][r] * s320;
        }
      }
    }
  }

  // V_out channel 0 = 0
  { int el = t >> 6, o = t & 63;
    vosh[el*584 + o*9] = 0.f; }

  // ---- MLP via MFMA (M=4 real rows padded to 16) ----
  const unsigned short* hp = (ml < 4) ? &hsh[ml*264] : zrow;
  {
    f32x4 c = (f32x4){0,0,0,0};
    const unsigned short* bb = w1f + ((size_t)(ntile*8)*64 + lane)*8;
    #pragma unroll
    for (int ks = 0; ks < 8; ks++) {
      short8 bf = *(const short8*)(bb + ks*512);
      short8 af = *(const short8*)(hp + ks*32 + qr*8);
      c = __builtin_amdgcn_mfma_f32_16x16x32_bf16(af, bf, c, 0, 0, 0);
    }
    #pragma unroll
    for (int r = 0; r < 4; r++) {
      int row = qr*4 + r;
      if (row < 4) {
        float v = c[r] * 0.0625f;
        float sv = v / (1.f + expf(-v)) * inv_actc;
        h1sh[row*72 + ntile*16 + ml] = f2bf(sv);
      }
    }
  }
  __syncthreads();
  {
    f32x4 c = (f32x4){0,0,0,0};
    const unsigned short* ap = (ml < 4) ? &h1sh[ml*72] : zrow;
    const unsigned short* bb = w2f + ((size_t)(ntile*2)*64 + lane)*8;
    #pragma unroll
    for (int ks = 0; ks < 2; ks++) {
      short8 bf = *(const short8*)(bb + ks*512);
      short8 af = *(const short8*)(ap + ks*32 + qr*8);
      c = __builtin_amdgcn_mfma_f32_16x16x32_bf16(af, bf, c, 0, 0, 0);
    }
    #pragma unroll
    for (int r = 0; r < 4; r++) {
      int row = qr*4 + r;
      if (row < 4) {
        float v = c[r] * 0.125f;
        float sv = v / (1.f + expf(-v)) * inv_actc;
        h2sh[row*72 + ntile*16 + ml] = f2bf(sv);
      }
    }
  }
  __syncthreads();
  {
    f32x4 c = (f32x4){0,0,0,0};
    const unsigned short* ap = (ml < 4) ? &h2sh[ml*72] : zrow;
    const unsigned short* bb = w3f + ((size_t)(ntile*2)*64 + lane)*8;
    #pragma unroll
    for (int ks = 0; ks < 2; ks++) {
      short8 bf = *(const short8*)(bb + ks*512);
      short8 af = *(const short8*)(ap + ks*32 + qr*8);
      c = __builtin_amdgcn_mfma_f32_16x16x32_bf16(af, bf, c, 0, 0, 0);
    }
    #pragma unroll
    for (int r = 0; r < 4; r++) {
      int row = qr*4 + r;
      if (row < 4) {
        float v = c[r] * 0.125f;
        out[(size_t)(e0+row)*64 + ntile*16 + ml] = ush[row] * v;
      }
    }
  }

  // coalesced float4 store of staged V_out
  for (int q = t; q < 576; q += 256) {
    int el = q / 144, i4 = q - (q/144)*144;
    ((f32x4*)(out + E64 + (size_t)(e0+el)*576))[i4] = ((f32x4*)(vosh + el*584))[i4];
  }
}

extern "C" void kernel_launch(void* const* d_in, const int* in_sizes, int n_in,
                              void* d_out, int out_size, void* d_ws, size_t ws_size,
                              hipStream_t stream)
{
  const float* vec     = (const float*)d_in[0];
  const float* x       = (const float*)d_in[1];
  const float* V       = (const float*)d_in[2];
  const int*   senders = (const int*)  d_in[3];
  const float* Ww      = (const float*)d_in[4];
  const float* W1      = (const float*)d_in[5];
  const float* W2      = (const float*)d_in[6];
  const float* W3      = (const float*)d_in[7];
  const float* Wv1     = (const float*)d_in[8];
  const float* Wv2     = (const float*)d_in[9];
  float* out = (float*)d_out;
  const int E = in_sizes[0] / 3;

  // ---- workspace layout ----
  char* base = (char*)d_ws;
  float* node_agg = (float*)(base);                        // 4 MB  [node][n][k]
  float* w_ws     = (float*)(base + (4<<20));              // 4 MB
  float* cg       = (float*)(base + (8<<20));              // 573 floats
  float* actp     = (float*)(base + (8<<20) + 4096);       // 8 floats
  int* counts     = (int*)  (base + (8<<20) + 8192);       // 1024 ints
  int* elist      = (int*)  (base + (8<<20) + 12288);      // 256 KB
  unsigned short* wv1f = (unsigned short*)(base + (8<<20) + 278528);
  unsigned short* wv2f = (unsigned short*)(base + (8<<20) + 319488);
  unsigned short* w1f  = (unsigned short*)(base + (8<<20) + 360448);
  unsigned short* w2f  = (unsigned short*)(base + (8<<20) + 393216);
  unsigned short* w3f  = (unsigned short*)(base + (8<<20) + 401408);

  prep<<<53, 256, 0, stream>>>(Wv1, Wv2, W1, W2, W3,
                               wv1f, wv2f, w1f, w2f, w3f, cg, actp, counts);
  edgepass<<<(E+3)/4, 256, 0, stream>>>(x, Ww, senders, w_ws, counts, elist, E);
  k_node<<<NNODES, 256, 0, stream>>>(vec, w_ws, counts, elist, node_agg);
  edge_main<<<E/EB, 256, 0, stream>>>(vec, x, V, senders, node_agg, cg,
                                      wv1f, wv2f, w1f, w2f, w3f, out, E, actp);
}